// Round 1
// baseline (1472.165 us; speedup 1.0000x reference)
//
#include <hip/hip_runtime.h>
#include <math.h>

typedef __bf16 bf16;
typedef __bf16 bf16x4 __attribute__((ext_vector_type(4)));
typedef __bf16 bf16x8 __attribute__((ext_vector_type(8)));
typedef float  f32x4  __attribute__((ext_vector_type(4)));

__device__ __forceinline__ f32x4 mfma16x16x32(bf16x8 a, bf16x8 b, f32x4 c) {
  return __builtin_amdgcn_mfma_f32_16x16x32_bf16(a, b, c, 0, 0, 0);
}

// ---------------- fp32 -> bf16 convert ----------------
__global__ void __launch_bounds__(256) convert_bf16_kernel(const float* __restrict__ in,
                                                           bf16* __restrict__ out, int n4) {
  int i = blockIdx.x * 256 + threadIdx.x;
  if (i < n4) {
    float4 f = ((const float4*)in)[i];
    bf16x4 b = {(bf16)f.x, (bf16)f.y, (bf16)f.z, (bf16)f.w};
    ((bf16x4*)out)[i] = b;
  }
}

// ---------------- projection GEMM: Out[1024 x dX] = Hb[1024x1024] @ P[1024 x dX] ----------------
// bf16 A from ws, fp32 P transposed-staged into LDS as bf16. Tile 64 rows x 256 cols.
__global__ void __launch_bounds__(256) proj_gemm_kernel(const bf16* __restrict__ Hb,
                                                        const float* __restrict__ P,
                                                        bf16* __restrict__ Out,
                                                        int dX, int strideOut) {
  constexpr int BK = 64, LDT = BK + 8;
  __shared__ bf16 Alds[64 * LDT];
  __shared__ bf16 Blds[256 * LDT];
  const int tid = threadIdx.x;
  const int w = tid >> 6, lane = tid & 63;
  const int q = lane >> 4, c = lane & 15;
  const int row0 = blockIdx.x * 64, col0 = blockIdx.y * 256;

  f32x4 acc[4][4] = {};

  for (int kt = 0; kt < 16; ++kt) {
    const int k0 = kt * BK;
#pragma unroll
    for (int i = 0; i < 2; ++i) {        // A: 64 rows x 64 k bf16, 8-elem granules
      int g = i * 256 + tid;
      int row = g >> 3, kg = (g & 7) * 8;
      *(uint4*)&Alds[row * LDT + kg] = *(const uint4*)&Hb[(size_t)(row0 + row) * 1024 + k0 + kg];
    }
#pragma unroll
    for (int i = 0; i < 16; ++i) {       // B: P[k0..k0+63][col0..col0+255], transpose into [col][k]
      int g = i * 256 + tid;
      int kl = g >> 6;
      int cb = (g & 63) * 4;
      float4 f = {0.f, 0.f, 0.f, 0.f};
      if (col0 + cb < dX) f = *(const float4*)&P[(size_t)(k0 + kl) * dX + col0 + cb];
      Blds[(cb + 0) * LDT + kl] = (bf16)f.x;
      Blds[(cb + 1) * LDT + kl] = (bf16)f.y;
      Blds[(cb + 2) * LDT + kl] = (bf16)f.z;
      Blds[(cb + 3) * LDT + kl] = (bf16)f.w;
    }
    __syncthreads();
#pragma unroll
    for (int ks = 0; ks < 2; ++ks) {
      bf16x8 af[4], bfr[4];
#pragma unroll
      for (int rt = 0; rt < 4; ++rt)
        af[rt] = *(const bf16x8*)&Alds[(rt * 16 + c) * LDT + ks * 32 + q * 8];
#pragma unroll
      for (int ct = 0; ct < 4; ++ct)
        bfr[ct] = *(const bf16x8*)&Blds[(w * 64 + ct * 16 + c) * LDT + ks * 32 + q * 8];
#pragma unroll
      for (int rt = 0; rt < 4; ++rt)
#pragma unroll
        for (int ct = 0; ct < 4; ++ct)
          acc[rt][ct] = mfma16x16x32(af[rt], bfr[ct], acc[rt][ct]);
    }
    __syncthreads();
  }

#pragma unroll
  for (int rt = 0; rt < 4; ++rt)
#pragma unroll
    for (int ct = 0; ct < 4; ++ct)
#pragma unroll
      for (int r = 0; r < 4; ++r) {
        int col = col0 + w * 64 + ct * 16 + c;
        if (col < dX) {
          int row = row0 + rt * 16 + q * 4 + r;
          Out[(size_t)row * strideOut + col] = (bf16)acc[rt][ct][r];
        }
      }
}

// ---------------- fused GEMM + partial logsumexp ----------------
// S[row][v] = sum_k A[row][k] * Wrow(v)[k] + bias(v); per 64row x 256col block emit
// per-row (max, sumexp) partial into part[row*nchunk + chunk].
template <int KDIM>
__global__ void __launch_bounds__(256) gemm_lse_kernel(const bf16* __restrict__ A,
                                                       const float* __restrict__ W,
                                                       const float* __restrict__ W2,
                                                       const float* __restrict__ bias,
                                                       const float* __restrict__ bias2,
                                                       int splice, int V, int KW,
                                                       float2* __restrict__ part, int nchunk) {
  constexpr int BK = (KDIM >= 64) ? 64 : KDIM;
  constexpr int NIT = KDIM / BK;
  constexpr int LDT = BK + 8;
  __shared__ bf16 Alds[64 * LDT];
  __shared__ bf16 Blds[256 * LDT];
  __shared__ float2 wpart[4][64];

  const int tid = threadIdx.x;
  const int w = tid >> 6, lane = tid & 63;
  const int q = lane >> 4, c = lane & 15;
  const int row0 = blockIdx.x * 64;
  const int chunk = blockIdx.y;
  const int col0 = chunk * 256;

  f32x4 acc[4][4] = {};

  for (int kt = 0; kt < NIT; ++kt) {
    const int k0 = kt * BK;
    constexpr int AGPT = (64 * (BK / 8)) / 256;   // A granules (8 bf16) per thread
#pragma unroll
    for (int i = 0; i < AGPT; ++i) {
      int g = i * 256 + tid;
      int row = g / (BK / 8);
      int kg = (g % (BK / 8)) * 8;
      *(uint4*)&Alds[row * LDT + kg] = *(const uint4*)&A[(size_t)(row0 + row) * KDIM + k0 + kg];
    }
    constexpr int BGP = BK / 4;                   // float4 granules per col
#pragma unroll
    for (int i = 0; i < BGP; ++i) {               // 256*BGP granules / 256 threads
      int g = i * 256 + tid;
      int cl = g / BGP;
      int kq = (g % BGP) * 4;
      int v = col0 + cl;
      float4 f = {0.f, 0.f, 0.f, 0.f};
      if (v < V && (k0 + kq) < KW) {
        const float* src = (v < splice) ? (W + (size_t)v * KW) : (W2 + (size_t)(v - splice) * KW);
        f = *(const float4*)(src + k0 + kq);
      }
      bf16x4 b4 = {(bf16)f.x, (bf16)f.y, (bf16)f.z, (bf16)f.w};
      *(bf16x4*)&Blds[cl * LDT + kq] = b4;
    }
    __syncthreads();
#pragma unroll
    for (int ks = 0; ks < BK / 32; ++ks) {
      bf16x8 af[4], bfr[4];
#pragma unroll
      for (int rt = 0; rt < 4; ++rt)
        af[rt] = *(const bf16x8*)&Alds[(rt * 16 + c) * LDT + ks * 32 + q * 8];
#pragma unroll
      for (int ct = 0; ct < 4; ++ct)
        bfr[ct] = *(const bf16x8*)&Blds[(w * 64 + ct * 16 + c) * LDT + ks * 32 + q * 8];
#pragma unroll
      for (int rt = 0; rt < 4; ++rt)
#pragma unroll
        for (int ct = 0; ct < 4; ++ct)
          acc[rt][ct] = mfma16x16x32(af[rt], bfr[ct], acc[rt][ct]);
    }
    __syncthreads();
  }

  // epilogue: bias add + per-row (max,sumexp) over this block's 256 cols
  float bias_v[4];
#pragma unroll
  for (int ct = 0; ct < 4; ++ct) {
    int col = col0 + w * 64 + ct * 16 + c;
    bias_v[ct] = (col < V) ? ((col < splice) ? bias[col] : bias2[col - splice]) : 0.f;
  }
#pragma unroll
  for (int rt = 0; rt < 4; ++rt) {
#pragma unroll
    for (int r = 0; r < 4; ++r) {
      float vv[4];
      float m = -INFINITY;
#pragma unroll
      for (int ct = 0; ct < 4; ++ct) {
        int col = col0 + w * 64 + ct * 16 + c;
        vv[ct] = (col < V) ? (acc[rt][ct][r] + bias_v[ct]) : -INFINITY;
        m = fmaxf(m, vv[ct]);
      }
#pragma unroll
      for (int off = 1; off <= 8; off <<= 1) m = fmaxf(m, __shfl_xor(m, off));
      float s = 0.f;
#pragma unroll
      for (int ct = 0; ct < 4; ++ct)
        if (vv[ct] > -INFINITY) s += expf(vv[ct] - m);
#pragma unroll
      for (int off = 1; off <= 8; off <<= 1) s += __shfl_xor(s, off);
      if (c == 0) wpart[w][rt * 16 + q * 4 + r] = make_float2(m, s);
    }
  }
  __syncthreads();
  if (tid < 64) {
    float M = -INFINITY;
#pragma unroll
    for (int ww = 0; ww < 4; ++ww) M = fmaxf(M, wpart[ww][tid].x);
    float S = 0.f;
#pragma unroll
    for (int ww = 0; ww < 4; ++ww) {
      float2 p = wpart[ww][tid];
      if (p.y > 0.f) S += p.y * expf(p.x - M);
    }
    part[(size_t)(row0 + tid) * nchunk + chunk] = make_float2(M, S);
  }
}

// ---------------- final combine: lse reduce + gather dots + nll ----------------
__device__ __forceinline__ float wave_max64(float v) {
#pragma unroll
  for (int off = 1; off < 64; off <<= 1) v = fmaxf(v, __shfl_xor(v, off));
  return v;
}
__device__ __forceinline__ float wave_sum64(float v) {
#pragma unroll
  for (int off = 1; off < 64; off <<= 1) v += __shfl_xor(v, off);
  return v;
}
__device__ float lse_from_parts(const float2* __restrict__ p, int n) {
  int lane = threadIdx.x & 63;
  float m = -INFINITY;
  for (int i = lane; i < n; i += 64) m = fmaxf(m, p[i].x);
  m = wave_max64(m);
  float s = 0.f;
  for (int i = lane; i < n; i += 64) {
    float2 v = p[i];
    if (v.y > 0.f) s += v.y * expf(v.x - m);
  }
  s = wave_sum64(s);
  return m + logf(s);
}
__device__ float dot_bw(const bf16* __restrict__ h, const float* __restrict__ wv, int K) {
  int lane = threadIdx.x & 63;
  float s = 0.f;
  for (int i = lane; i < K; i += 64) s += (float)h[i] * wv[i];
  return wave_sum64(s);
}

__global__ void __launch_bounds__(256) final_kernel(
    const int* __restrict__ target,
    const float2* __restrict__ pH, const float2* __restrict__ p1,
    const float2* __restrict__ p2, const float2* __restrict__ p3,
    const bf16* __restrict__ h0, const bf16* __restrict__ h1,
    const bf16* __restrict__ h2, const bf16* __restrict__ h3,
    const float* __restrict__ head_w, const float* __restrict__ head_b,
    const float* __restrict__ cluster_w, const float* __restrict__ cluster_b,
    const float* __restrict__ w1, const float* __restrict__ b1,
    const float* __restrict__ w2, const float* __restrict__ b2,
    const float* __restrict__ w3, const float* __restrict__ b3,
    float* __restrict__ out) {
  int wv = threadIdx.x >> 6, lane = threadIdx.x & 63;
  int row = blockIdx.x * 4 + wv;
  int t = target[row];

  float lseH = lse_from_parts(pH + (size_t)row * 79, 79);
  float lp;
  if (t < 20000) {
    float sel = dot_bw(h0 + (size_t)row * 1024, head_w + (size_t)t * 1024, 1024) + head_b[t];
    lp = sel - lseH;
  } else {
    int i, L, KW, nch;
    const float2* pp; const float* W; const float* Bb; const bf16* H;
    if (t < 40000)        { i = 1; L = 20000;  KW = 256; nch = 79;  pp = p1; W = w1; Bb = b1; H = h1 + (size_t)row * 256; }
    else if (t < 200000)  { i = 2; L = 40000;  KW = 64;  nch = 625; pp = p2; W = w2; Bb = b2; H = h2 + (size_t)row * 64; }
    else                  { i = 3; L = 200000; KW = 16;  nch = 265; pp = p3; W = w3; Bb = b3; H = h3 + (size_t)row * 32; }
    float lseT = lse_from_parts(pp + (size_t)row * nch, nch);
    int ti = t - L;
    float tsel = dot_bw(H, W + (size_t)ti * KW, KW) + Bb[ti];
    int j = 3 - i;  // head_lp[:, -i] == cluster row (3-i)
    float csel = dot_bw(h0 + (size_t)row * 1024, cluster_w + (size_t)j * 1024, 1024) + cluster_b[j];
    lp = (csel - lseH) + (tsel - lseT);
  }
  if (lane == 0) out[row] = -lp;
}

extern "C" void kernel_launch(void* const* d_in, const int* in_sizes, int n_in,
                              void* d_out, int out_size, void* d_ws, size_t ws_size,
                              hipStream_t stream) {
  (void)in_sizes; (void)n_in; (void)out_size; (void)ws_size;
  const float* hidden    = (const float*)d_in[0];
  const int*   target    = (const int*)d_in[1];
  const float* head_w    = (const float*)d_in[2];
  const float* head_b    = (const float*)d_in[3];
  const float* cluster_w = (const float*)d_in[4];
  const float* cluster_b = (const float*)d_in[5];
  const float* proj0     = (const float*)d_in[6];
  const float* proj1     = (const float*)d_in[7];
  const float* proj2     = (const float*)d_in[8];
  const float* proj3     = (const float*)d_in[9];
  const float* w1 = (const float*)d_in[10];
  const float* b1 = (const float*)d_in[11];
  const float* w2 = (const float*)d_in[12];
  const float* b2 = (const float*)d_in[13];
  const float* w3 = (const float*)d_in[14];
  const float* b3 = (const float*)d_in[15];
  float* out = (float*)d_out;

  char* p = (char*)d_ws;
  bf16* hid_b = (bf16*)p; p += (size_t)1024 * 1024 * 2;
  bf16* h0    = (bf16*)p; p += (size_t)1024 * 1024 * 2;
  bf16* h1    = (bf16*)p; p += (size_t)1024 * 256 * 2;
  bf16* h2    = (bf16*)p; p += (size_t)1024 * 64 * 2;
  bf16* h3    = (bf16*)p; p += (size_t)1024 * 32 * 2;   // K padded 16->32 with zeros
  float2* pH  = (float2*)p; p += (size_t)1024 * 79 * 8;
  float2* p1  = (float2*)p; p += (size_t)1024 * 79 * 8;
  float2* p2  = (float2*)p; p += (size_t)1024 * 625 * 8;
  float2* p3  = (float2*)p; p += (size_t)1024 * 265 * 8;

  hipMemsetAsync(h3, 0, (size_t)1024 * 32 * 2, stream);
  convert_bf16_kernel<<<1024, 256, 0, stream>>>(hidden, hid_b, 1024 * 1024 / 4);

  proj_gemm_kernel<<<dim3(16, 4), 256, 0, stream>>>(hid_b, proj0, h0, 1024, 1024);
  proj_gemm_kernel<<<dim3(16, 1), 256, 0, stream>>>(hid_b, proj1, h1, 256, 256);
  proj_gemm_kernel<<<dim3(16, 1), 256, 0, stream>>>(hid_b, proj2, h2, 64, 64);
  proj_gemm_kernel<<<dim3(16, 1), 256, 0, stream>>>(hid_b, proj3, h3, 16, 32);

  const int BIGSPLICE = 0x40000000;
  // head: cols 0..19999 from head_w/head_b, 20000..20002 from cluster_w/cluster_b
  gemm_lse_kernel<1024><<<dim3(16, 79), 256, 0, stream>>>(h0, head_w, cluster_w, head_b, cluster_b,
                                                          20000, 20003, 1024, pH, 79);
  gemm_lse_kernel<256><<<dim3(16, 79), 256, 0, stream>>>(h1, w1, w1, b1, b1,
                                                         BIGSPLICE, 20000, 256, p1, 79);
  gemm_lse_kernel<64><<<dim3(16, 625), 256, 0, stream>>>(h2, w2, w2, b2, b2,
                                                         BIGSPLICE, 160000, 64, p2, 625);
  gemm_lse_kernel<32><<<dim3(16, 265), 256, 0, stream>>>(h3, w3, w3, b3, b3,
                                                         BIGSPLICE, 67735, 16, p3, 265);

  final_kernel<<<256, 256, 0, stream>>>(target, pH, p1, p2, p3, h0, h1, h2, h3,
                                        head_w, head_b, cluster_w, cluster_b,
                                        w1, b1, w2, b2, w3, b3, out);
}

// Round 2
// 984.534 us; speedup vs baseline: 1.4953x; 1.4953x over previous
//
#include <hip/hip_runtime.h>
#include <math.h>

typedef __bf16 bf16;
typedef __bf16 bf16x4 __attribute__((ext_vector_type(4)));
typedef __bf16 bf16x8 __attribute__((ext_vector_type(8)));
typedef float  f32x4  __attribute__((ext_vector_type(4)));

__device__ __forceinline__ f32x4 mfma16x16x32(bf16x8 a, bf16x8 b, f32x4 c) {
  return __builtin_amdgcn_mfma_f32_16x16x32_bf16(a, b, c, 0, 0, 0);
}

// ---------------- fp32 -> bf16 convert ----------------
__global__ void __launch_bounds__(256) convert_bf16_kernel(const float* __restrict__ in,
                                                           bf16* __restrict__ out, int n4) {
  int i = blockIdx.x * 256 + threadIdx.x;
  if (i < n4) {
    float4 f = ((const float4*)in)[i];
    bf16x4 b = {(bf16)f.x, (bf16)f.y, (bf16)f.z, (bf16)f.w};
    ((bf16x4*)out)[i] = b;
  }
}

// ---------------- projection GEMM: Out[1024 x dX] = Hb[1024x1024] @ P[1024 x dX] ----------------
__global__ void __launch_bounds__(256) proj_gemm_kernel(const bf16* __restrict__ Hb,
                                                        const float* __restrict__ P,
                                                        bf16* __restrict__ Out,
                                                        int dX, int strideOut) {
  constexpr int BK = 64, LDT = BK + 8;
  __shared__ bf16 Alds[64 * LDT];
  __shared__ bf16 Blds[256 * LDT];
  const int tid = threadIdx.x;
  const int w = tid >> 6, lane = tid & 63;
  const int q = lane >> 4, c = lane & 15;
  const int row0 = blockIdx.x * 64, col0 = blockIdx.y * 256;

  f32x4 acc[4][4] = {};

  for (int kt = 0; kt < 16; ++kt) {
    const int k0 = kt * BK;
#pragma unroll
    for (int i = 0; i < 2; ++i) {
      int g = i * 256 + tid;
      int row = g >> 3, kg = (g & 7) * 8;
      *(uint4*)&Alds[row * LDT + kg] = *(const uint4*)&Hb[(size_t)(row0 + row) * 1024 + k0 + kg];
    }
#pragma unroll
    for (int i = 0; i < 16; ++i) {
      int g = i * 256 + tid;
      int kl = g >> 6;
      int cb = (g & 63) * 4;
      float4 f = {0.f, 0.f, 0.f, 0.f};
      if (col0 + cb < dX) f = *(const float4*)&P[(size_t)(k0 + kl) * dX + col0 + cb];
      Blds[(cb + 0) * LDT + kl] = (bf16)f.x;
      Blds[(cb + 1) * LDT + kl] = (bf16)f.y;
      Blds[(cb + 2) * LDT + kl] = (bf16)f.z;
      Blds[(cb + 3) * LDT + kl] = (bf16)f.w;
    }
    __syncthreads();
#pragma unroll
    for (int ks = 0; ks < 2; ++ks) {
      bf16x8 af[4], bfr[4];
#pragma unroll
      for (int rt = 0; rt < 4; ++rt)
        af[rt] = *(const bf16x8*)&Alds[(rt * 16 + c) * LDT + ks * 32 + q * 8];
#pragma unroll
      for (int ct = 0; ct < 4; ++ct)
        bfr[ct] = *(const bf16x8*)&Blds[(w * 64 + ct * 16 + c) * LDT + ks * 32 + q * 8];
#pragma unroll
      for (int rt = 0; rt < 4; ++rt)
#pragma unroll
        for (int ct = 0; ct < 4; ++ct)
          acc[rt][ct] = mfma16x16x32(af[rt], bfr[ct], acc[rt][ct]);
    }
    __syncthreads();
  }

#pragma unroll
  for (int rt = 0; rt < 4; ++rt)
#pragma unroll
    for (int ct = 0; ct < 4; ++ct)
#pragma unroll
      for (int r = 0; r < 4; ++r) {
        int col = col0 + w * 64 + ct * 16 + c;
        if (col < dX) {
          int row = row0 + rt * 16 + q * 4 + r;
          Out[(size_t)row * strideOut + col] = (bf16)acc[rt][ct][r];
        }
      }
}

// ---------------- fused GEMM + per-chunk logsumexp ----------------
// 128x128 tile, 4 waves in 2x2. LDS granule layout pos = kg*128 + (idx^kg):
// coalesced global reads AND conflict-free b128 LDS writes/reads.
// Grid is flat, swizzled so all 8 row-blocks of a col-chunk share f%8 (same XCD
// under round-robin dispatch -> W chunk fetched from HBM once).
template <int KDIM>
__global__ void __launch_bounds__(256) gemm_lse_kernel(const bf16* __restrict__ A,
                                                       const float* __restrict__ W,
                                                       const float* __restrict__ W2,
                                                       const float* __restrict__ bias,
                                                       const float* __restrict__ bias2,
                                                       int splice, int V, int KW,
                                                       float* __restrict__ part, int nchunk) {
  constexpr int BK = (KDIM < 64) ? KDIM : 64;   // 32 or 64
  constexpr int KG = BK / 8;                    // granules of 8 k
  constexpr int NIT = KDIM / BK;
  __shared__ bf16 Alds[KG * 128 * 8];
  __shared__ bf16 Blds[KG * 128 * 8];
  __shared__ float2 wpart[2][128];

  const int tid = threadIdx.x;
  const int w = tid >> 6, lane = tid & 63;
  const int q = lane >> 4, c = lane & 15;
  const int wr = w >> 1, wc = w & 1;

  int f = blockIdx.x;
  int xr = f & 7;
  int rest = f >> 3;
  int rb = rest & 7;
  int cq = rest >> 3;
  int chunk = cq * 8 + xr;
  if (chunk >= nchunk) return;
  const int row0 = rb * 128;
  const int col0 = chunk * 128;

  f32x4 acc[4][4] = {};

  for (int kt = 0; kt < NIT; ++kt) {
    const int k0 = kt * BK;
#pragma unroll
    for (int i = 0; i < KG / 2; ++i) {          // A stage: g -> (row=g/KG, kg=g%KG)
      int g = i * 256 + tid;
      int row = g / KG, kg = g % KG;
      uint4 v = *(const uint4*)&A[(size_t)(row0 + row) * KDIM + k0 + kg * 8];
      int pos = kg * 128 + (row ^ kg);
      *(uint4*)&Alds[pos * 8] = v;
    }
#pragma unroll
    for (int i = 0; i < KG / 2; ++i) {          // B stage (fp32 -> bf16)
      int g = i * 256 + tid;
      int col = g / KG, kg = g % KG;
      int vcol = col0 + col;
      float4 f0 = {0.f, 0.f, 0.f, 0.f}, f1 = {0.f, 0.f, 0.f, 0.f};
      if (vcol < V && k0 + kg * 8 < KW) {
        const float* src = (vcol < splice) ? (W + (size_t)vcol * KW)
                                           : (W2 + (size_t)(vcol - splice) * KW);
        f0 = *(const float4*)(src + k0 + kg * 8);
        f1 = *(const float4*)(src + k0 + kg * 8 + 4);
      }
      bf16x8 b8 = {(bf16)f0.x, (bf16)f0.y, (bf16)f0.z, (bf16)f0.w,
                   (bf16)f1.x, (bf16)f1.y, (bf16)f1.z, (bf16)f1.w};
      int pos = kg * 128 + (col ^ kg);
      *(bf16x8*)&Blds[pos * 8] = b8;
    }
    __syncthreads();
#pragma unroll
    for (int ks = 0; ks < BK / 32; ++ks) {
      const int kq = ks * 4 + q;
      bf16x8 af[4], bfr[4];
#pragma unroll
      for (int rt = 0; rt < 4; ++rt) {
        int pos = kq * 128 + ((wr * 64 + rt * 16 + c) ^ kq);
        af[rt] = *(const bf16x8*)&Alds[pos * 8];
      }
#pragma unroll
      for (int ct = 0; ct < 4; ++ct) {
        int pos = kq * 128 + ((wc * 64 + ct * 16 + c) ^ kq);
        bfr[ct] = *(const bf16x8*)&Blds[pos * 8];
      }
#pragma unroll
      for (int rt = 0; rt < 4; ++rt)
#pragma unroll
        for (int ct = 0; ct < 4; ++ct)
          acc[rt][ct] = mfma16x16x32(af[rt], bfr[ct], acc[rt][ct]);
    }
    __syncthreads();
  }

  // epilogue: bias + per-row (max,sumexp) over this block's 128 cols -> chunk lse
  float bv[4];
#pragma unroll
  for (int ct = 0; ct < 4; ++ct) {
    int colg = col0 + wc * 64 + ct * 16 + c;
    bv[ct] = (colg < V) ? ((colg < splice) ? bias[colg] : bias2[colg - splice]) : 0.f;
  }
#pragma unroll
  for (int rt = 0; rt < 4; ++rt) {
#pragma unroll
    for (int r = 0; r < 4; ++r) {
      float vv[4];
      float m = -INFINITY;
#pragma unroll
      for (int ct = 0; ct < 4; ++ct) {
        int colg = col0 + wc * 64 + ct * 16 + c;
        vv[ct] = (colg < V) ? (acc[rt][ct][r] + bv[ct]) : -INFINITY;
        m = fmaxf(m, vv[ct]);
      }
#pragma unroll
      for (int off = 1; off <= 8; off <<= 1) m = fmaxf(m, __shfl_xor(m, off));
      float s = 0.f;
#pragma unroll
      for (int ct = 0; ct < 4; ++ct)
        if (vv[ct] > -INFINITY) s += expf(vv[ct] - m);
#pragma unroll
      for (int off = 1; off <= 8; off <<= 1) s += __shfl_xor(s, off);
      if (c == 0) wpart[wc][wr * 64 + rt * 16 + q * 4 + r] = make_float2(m, s);
    }
  }
  __syncthreads();
  if (tid < 128) {
    float2 a = wpart[0][tid], b = wpart[1][tid];
    float m = fmaxf(a.x, b.x);
    float s = (a.y > 0.f ? a.y * expf(a.x - m) : 0.f) +
              (b.y > 0.f ? b.y * expf(b.x - m) : 0.f);
    part[(size_t)(row0 + tid) * nchunk + chunk] = m + logf(s);
  }
}

// ---------------- final combine ----------------
__device__ __forceinline__ float wave_max64(float v) {
#pragma unroll
  for (int off = 1; off < 64; off <<= 1) v = fmaxf(v, __shfl_xor(v, off));
  return v;
}
__device__ __forceinline__ float wave_sum64(float v) {
#pragma unroll
  for (int off = 1; off < 64; off <<= 1) v += __shfl_xor(v, off);
  return v;
}
__device__ float lse_chunks(const float* __restrict__ p, int n) {
  int lane = threadIdx.x & 63;
  float m = -INFINITY;
  for (int i = lane; i < n; i += 64) m = fmaxf(m, p[i]);
  m = wave_max64(m);
  float s = 0.f;
  for (int i = lane; i < n; i += 64) s += expf(p[i] - m);
  s = wave_sum64(s);
  return m + logf(s);
}
__device__ float dot_bw(const bf16* __restrict__ h, const float* __restrict__ wv, int K) {
  int lane = threadIdx.x & 63;
  float s = 0.f;
  for (int i = lane; i < K; i += 64) s += (float)h[i] * wv[i];
  return wave_sum64(s);
}

__global__ void __launch_bounds__(256) final_kernel(
    const int* __restrict__ target,
    const float* __restrict__ pH, const float* __restrict__ p1,
    const float* __restrict__ p2, const float* __restrict__ p3,
    const bf16* __restrict__ h0, const bf16* __restrict__ h1,
    const bf16* __restrict__ h2, const bf16* __restrict__ h3,
    const float* __restrict__ head_w, const float* __restrict__ head_b,
    const float* __restrict__ cluster_w, const float* __restrict__ cluster_b,
    const float* __restrict__ w1, const float* __restrict__ b1,
    const float* __restrict__ w2, const float* __restrict__ b2,
    const float* __restrict__ w3, const float* __restrict__ b3,
    float* __restrict__ out) {
  int wv = threadIdx.x >> 6, lane = threadIdx.x & 63;
  int row = blockIdx.x * 4 + wv;
  int t = target[row];

  float lseH = lse_chunks(pH + (size_t)row * 157, 157);
  float lp;
  if (t < 20000) {
    float sel = dot_bw(h0 + (size_t)row * 1024, head_w + (size_t)t * 1024, 1024) + head_b[t];
    lp = sel - lseH;
  } else {
    int i, L, KW, nch;
    const float* pp; const float* W; const float* Bb; const bf16* H;
    if (t < 40000)        { i = 1; L = 20000;  KW = 256; nch = 157;  pp = p1; W = w1; Bb = b1; H = h1 + (size_t)row * 256; }
    else if (t < 200000)  { i = 2; L = 40000;  KW = 64;  nch = 1250; pp = p2; W = w2; Bb = b2; H = h2 + (size_t)row * 64; }
    else                  { i = 3; L = 200000; KW = 16;  nch = 530;  pp = p3; W = w3; Bb = b3; H = h3 + (size_t)row * 32; }
    float lseT = lse_chunks(pp + (size_t)row * nch, nch);
    int ti = t - L;
    float tsel = dot_bw(H, W + (size_t)ti * KW, KW) + Bb[ti];
    int j = 3 - i;  // head_lp[:, -i] == cluster row (3-i)
    float csel = dot_bw(h0 + (size_t)row * 1024, cluster_w + (size_t)j * 1024, 1024) + cluster_b[j];
    lp = (csel - lseH) + (tsel - lseT);
  }
  if (lane == 0) out[row] = -lp;
}

extern "C" void kernel_launch(void* const* d_in, const int* in_sizes, int n_in,
                              void* d_out, int out_size, void* d_ws, size_t ws_size,
                              hipStream_t stream) {
  (void)in_sizes; (void)n_in; (void)out_size; (void)ws_size;
  const float* hidden    = (const float*)d_in[0];
  const int*   target    = (const int*)d_in[1];
  const float* head_w    = (const float*)d_in[2];
  const float* head_b    = (const float*)d_in[3];
  const float* cluster_w = (const float*)d_in[4];
  const float* cluster_b = (const float*)d_in[5];
  const float* proj0     = (const float*)d_in[6];
  const float* proj1     = (const float*)d_in[7];
  const float* proj2     = (const float*)d_in[8];
  const float* proj3     = (const float*)d_in[9];
  const float* w1 = (const float*)d_in[10];
  const float* b1 = (const float*)d_in[11];
  const float* w2 = (const float*)d_in[12];
  const float* b2 = (const float*)d_in[13];
  const float* w3 = (const float*)d_in[14];
  const float* b3 = (const float*)d_in[15];
  float* out = (float*)d_out;

  char* p = (char*)d_ws;
  bf16* hid_b = (bf16*)p; p += (size_t)1024 * 1024 * 2;
  bf16* h0    = (bf16*)p; p += (size_t)1024 * 1024 * 2;
  bf16* h1    = (bf16*)p; p += (size_t)1024 * 256 * 2;
  bf16* h2    = (bf16*)p; p += (size_t)1024 * 64 * 2;
  bf16* h3    = (bf16*)p; p += (size_t)1024 * 32 * 2;   // K padded 16->32 with zeros
  float* pH   = (float*)p; p += (size_t)1024 * 157 * 4;
  float* p1   = (float*)p; p += (size_t)1024 * 157 * 4;
  float* p2   = (float*)p; p += (size_t)1024 * 1250 * 4;
  float* p3   = (float*)p; p += (size_t)1024 * 530 * 4;

  hipMemsetAsync(h3, 0, (size_t)1024 * 32 * 2, stream);
  convert_bf16_kernel<<<1024, 256, 0, stream>>>(hidden, hid_b, 1024 * 1024 / 4);

  proj_gemm_kernel<<<dim3(16, 4), 256, 0, stream>>>(hid_b, proj0, h0, 1024, 1024);
  proj_gemm_kernel<<<dim3(16, 1), 256, 0, stream>>>(hid_b, proj1, h1, 256, 256);
  proj_gemm_kernel<<<dim3(16, 1), 256, 0, stream>>>(hid_b, proj2, h2, 64, 64);
  proj_gemm_kernel<<<dim3(16, 1), 256, 0, stream>>>(hid_b, proj3, h3, 16, 32);

  const int BIGSPLICE = 0x40000000;
  // grid = 64 * ceil(nchunk/8); flat swizzle keeps col-chunk on one XCD
  gemm_lse_kernel<1024><<<64 * 20, 256, 0, stream>>>(h0, head_w, cluster_w, head_b, cluster_b,
                                                     20000, 20003, 1024, pH, 157);
  gemm_lse_kernel<256><<<64 * 20, 256, 0, stream>>>(h1, w1, w1, b1, b1,
                                                    BIGSPLICE, 20000, 256, p1, 157);
  gemm_lse_kernel<64><<<64 * 157, 256, 0, stream>>>(h2, w2, w2, b2, b2,
                                                    BIGSPLICE, 160000, 64, p2, 1250);
  gemm_lse_kernel<32><<<64 * 67, 256, 0, stream>>>(h3, w3, w3, b3, b3,
                                                   BIGSPLICE, 67735, 16, p3, 530);

  final_kernel<<<256, 256, 0, stream>>>(target, pH, p1, p2, p3, h0, h1, h2, h3,
                                        head_w, head_b, cluster_w, cluster_b,
                                        w1, b1, w2, b2, w3, b3, out);
}

// Round 3
// 653.824 us; speedup vs baseline: 2.2516x; 1.5058x over previous
//
#include <hip/hip_runtime.h>
#include <math.h>

typedef __bf16 bf16;
typedef __bf16 bf16x4 __attribute__((ext_vector_type(4)));
typedef __bf16 bf16x8 __attribute__((ext_vector_type(8)));
typedef float  f32x4  __attribute__((ext_vector_type(4)));

__device__ __forceinline__ f32x4 mfma16x16x32(bf16x8 a, bf16x8 b, f32x4 c) {
  return __builtin_amdgcn_mfma_f32_16x16x32_bf16(a, b, c, 0, 0, 0);
}

// async 16B global -> LDS (lane data lands at ldsbase + lane*16)
__device__ __forceinline__ void async16(const bf16* gp, bf16* lp) {
  __builtin_amdgcn_global_load_lds(
      (const __attribute__((address_space(1))) void*)gp,
      (__attribute__((address_space(3))) void*)lp, 16, 0, 0);
}

// ---------------- fp32 -> bf16 convert ----------------
__global__ void __launch_bounds__(256) convert_bf16_kernel(const float* __restrict__ in,
                                                           bf16* __restrict__ out, int n4) {
  int i = blockIdx.x * 256 + threadIdx.x;
  if (i < n4) {
    float4 f = ((const float4*)in)[i];
    bf16x4 b = {(bf16)f.x, (bf16)f.y, (bf16)f.z, (bf16)f.w};
    ((bf16x4*)out)[i] = b;
  }
}

// w3 [67735][16] fp32 -> W3b [67840][32] bf16, k 16..31 zeroed
__global__ void __launch_bounds__(256) convert_w3_kernel(const float* __restrict__ w3,
                                                         bf16* __restrict__ W3b, int n4) {
  int i = blockIdx.x * 256 + threadIdx.x;
  if (i >= n4) return;
  int row = i >> 2, kq = i & 3;
  float4 f = *(const float4*)&w3[(size_t)i * 4];
  bf16x4 b = {(bf16)f.x, (bf16)f.y, (bf16)f.z, (bf16)f.w};
  *(bf16x4*)&W3b[(size_t)row * 32 + kq * 4] = b;
  bf16x4 z = {(bf16)0.f, (bf16)0.f, (bf16)0.f, (bf16)0.f};
  *(bf16x4*)&W3b[(size_t)row * 32 + 16 + kq * 4] = z;
}

// P [1024][dX] fp32 -> Pt [dXpad][1024] bf16 (transpose+convert)
__global__ void __launch_bounds__(256) transpose_convert_kernel(const float* __restrict__ P,
                                                                bf16* __restrict__ Pt, int dX) {
  __shared__ float t[32][33];
  int tx = threadIdx.x & 31, ty = threadIdx.x >> 5;
  int k0 = blockIdx.x * 32, c0 = blockIdx.y * 32;
#pragma unroll
  for (int s = 0; s < 4; ++s) {
    int k = k0 + ty + s * 8, col = c0 + tx;
    t[ty + s * 8][tx] = (col < dX) ? P[(size_t)k * dX + col] : 0.f;
  }
  __syncthreads();
#pragma unroll
  for (int s = 0; s < 4; ++s) {
    int colo = c0 + ty + s * 8;
    Pt[(size_t)colo * 1024 + k0 + tx] = (bf16)t[tx][ty + s * 8];
  }
}

// ---------------- unified MFMA GEMM (128x128 tile, async staging) ----------------
// A [*][KDIM], B [*][KDIM] row-major bf16, stride == KDIM.
// Staging: global_load_lds 16B; lane->granule mapping kg = j ^ swz(col) gives
// coalesced global reads AND conflict-free(2-way) ds_read_b128 fragments.
// LSE=true: per-chunk logsumexp partial. LSE=false: store bf16 C.
template <int KDIM, bool LSE>
__global__ void __launch_bounds__(256) gemm_kernel(
    const bf16* __restrict__ A, const bf16* __restrict__ B,
    const float* __restrict__ bias, const float* __restrict__ bias2,
    int splice, int V, float* __restrict__ part, int nchunk,
    bf16* __restrict__ Out, int strideOut, int dX) {
  constexpr int BK = (KDIM < 64) ? KDIM : 64;   // 32 or 64
  constexpr int KG = BK / 8;                    // 4 or 8 granules
  constexpr int NIT = KDIM / BK;
  __shared__ bf16 Alds[128 * BK];
  __shared__ bf16 Blds[128 * BK];
  __shared__ float2 wpart[2][128];

  const int tid = threadIdx.x;
  const int w = tid >> 6, lane = tid & 63;
  const int q = lane >> 4, c = lane & 15;
  const int wr = w >> 1, wc = w & 1;

  int f = blockIdx.x;
  int xr = f & 7, rb = (f >> 3) & 7, cq = f >> 6;
  int chunk = cq * 8 + xr;
  if (chunk >= nchunk) return;
  const int row0 = rb * 128, col0 = chunk * 128;

  f32x4 acc[4][4] = {};

  for (int kt = 0; kt < NIT; ++kt) {
    const int k0 = kt * BK;
#pragma unroll
    for (int i = 0; i < KG / 2; ++i) {
      int g = i * 256 + tid;
      int col = g / KG, j = g % KG;
      int kg = (KG == 8) ? (j ^ (col & 7)) : (j ^ ((col >> 1) & 3));
      bf16* abase = &Alds[(size_t)(g & ~63) * 8];
      bf16* bbase = &Blds[(size_t)(g & ~63) * 8];
      async16(A + (size_t)(row0 + col) * KDIM + k0 + kg * 8, abase);
      async16(B + (size_t)(col0 + col) * KDIM + k0 + kg * 8, bbase);
    }
    __syncthreads();
#pragma unroll
    for (int ks = 0; ks < BK / 32; ++ks) {
      bf16x8 af[4], bfr[4];
#pragma unroll
      for (int rt = 0; rt < 4; ++rt) {
        int rl = wr * 64 + rt * 16 + c;
        int kq = ks * 4 + q;
        int kg = (KG == 8) ? (kq ^ (rl & 7)) : (kq ^ ((rl >> 1) & 3));
        af[rt] = *(const bf16x8*)&Alds[((size_t)rl * KG + kg) * 8];
      }
#pragma unroll
      for (int ct = 0; ct < 4; ++ct) {
        int cl = wc * 64 + ct * 16 + c;
        int kq = ks * 4 + q;
        int kg = (KG == 8) ? (kq ^ (cl & 7)) : (kq ^ ((cl >> 1) & 3));
        bfr[ct] = *(const bf16x8*)&Blds[((size_t)cl * KG + kg) * 8];
      }
#pragma unroll
      for (int rt = 0; rt < 4; ++rt)
#pragma unroll
        for (int ct = 0; ct < 4; ++ct)
          acc[rt][ct] = mfma16x16x32(af[rt], bfr[ct], acc[rt][ct]);
    }
    __syncthreads();
  }

  if (!LSE) {
#pragma unroll
    for (int rt = 0; rt < 4; ++rt)
#pragma unroll
      for (int ct = 0; ct < 4; ++ct)
#pragma unroll
        for (int r = 0; r < 4; ++r) {
          int col = col0 + wc * 64 + ct * 16 + c;
          if (col < dX) {
            int row = row0 + wr * 64 + rt * 16 + q * 4 + r;
            Out[(size_t)row * strideOut + col] = (bf16)acc[rt][ct][r];
          }
        }
    return;
  }

  // LSE epilogue: bias + per-row (max,sumexp) over the 128 cols -> chunk lse
  float bv[4];
#pragma unroll
  for (int ct = 0; ct < 4; ++ct) {
    int colg = col0 + wc * 64 + ct * 16 + c;
    bv[ct] = (colg < V) ? ((colg < splice) ? bias[colg] : bias2[colg - splice]) : 0.f;
  }
#pragma unroll
  for (int rt = 0; rt < 4; ++rt) {
#pragma unroll
    for (int r = 0; r < 4; ++r) {
      float vv[4];
      float m = -INFINITY;
#pragma unroll
      for (int ct = 0; ct < 4; ++ct) {
        int colg = col0 + wc * 64 + ct * 16 + c;
        vv[ct] = (colg < V) ? (acc[rt][ct][r] + bv[ct]) : -INFINITY;
        m = fmaxf(m, vv[ct]);
      }
#pragma unroll
      for (int off = 1; off <= 8; off <<= 1) m = fmaxf(m, __shfl_xor(m, off));
      float s = 0.f;
#pragma unroll
      for (int ct = 0; ct < 4; ++ct)
        if (vv[ct] > -INFINITY) s += expf(vv[ct] - m);
#pragma unroll
      for (int off = 1; off <= 8; off <<= 1) s += __shfl_xor(s, off);
      if (c == 0) wpart[wc][wr * 64 + rt * 16 + q * 4 + r] = make_float2(m, s);
    }
  }
  __syncthreads();
  if (tid < 128) {
    float2 a = wpart[0][tid], b = wpart[1][tid];
    float m = fmaxf(a.x, b.x);
    float s = (a.y > 0.f ? a.y * expf(a.x - m) : 0.f) +
              (b.y > 0.f ? b.y * expf(b.x - m) : 0.f);
    part[(size_t)(row0 + tid) * nchunk + chunk] = m + logf(s);
  }
}

// ---------------- final combine ----------------
__device__ __forceinline__ float wave_max64(float v) {
#pragma unroll
  for (int off = 1; off < 64; off <<= 1) v = fmaxf(v, __shfl_xor(v, off));
  return v;
}
__device__ __forceinline__ float wave_sum64(float v) {
#pragma unroll
  for (int off = 1; off < 64; off <<= 1) v += __shfl_xor(v, off);
  return v;
}
__device__ float lse_chunks(const float* __restrict__ p, int n) {
  int lane = threadIdx.x & 63;
  float m = -INFINITY;
  for (int i = lane; i < n; i += 64) m = fmaxf(m, p[i]);
  m = wave_max64(m);
  float s = 0.f;
  for (int i = lane; i < n; i += 64) s += expf(p[i] - m);
  s = wave_sum64(s);
  return m + logf(s);
}
__device__ float dot_bw(const bf16* __restrict__ h, const float* __restrict__ wv, int K) {
  int lane = threadIdx.x & 63;
  float s = 0.f;
  for (int i = lane; i < K; i += 64) s += (float)h[i] * wv[i];
  return wave_sum64(s);
}

__global__ void __launch_bounds__(256) final_kernel(
    const int* __restrict__ target,
    const float* __restrict__ pH, const float* __restrict__ p1,
    const float* __restrict__ p2, const float* __restrict__ p3,
    const bf16* __restrict__ h0, const bf16* __restrict__ h1,
    const bf16* __restrict__ h2, const bf16* __restrict__ h3,
    const float* __restrict__ head_w, const float* __restrict__ head_b,
    const float* __restrict__ cluster_w, const float* __restrict__ cluster_b,
    const float* __restrict__ w1, const float* __restrict__ b1,
    const float* __restrict__ w2, const float* __restrict__ b2,
    const float* __restrict__ w3, const float* __restrict__ b3,
    float* __restrict__ out) {
  int wv = threadIdx.x >> 6, lane = threadIdx.x & 63;
  int row = blockIdx.x * 4 + wv;
  int t = target[row];

  float lseH = lse_chunks(pH + (size_t)row * 157, 157);
  float lp;
  if (t < 20000) {
    float sel = dot_bw(h0 + (size_t)row * 1024, head_w + (size_t)t * 1024, 1024) + head_b[t];
    lp = sel - lseH;
  } else {
    int i, L, KW, nch;
    const float* pp; const float* W; const float* Bb; const bf16* H;
    if (t < 40000)        { i = 1; L = 20000;  KW = 256; nch = 157;  pp = p1; W = w1; Bb = b1; H = h1 + (size_t)row * 256; }
    else if (t < 200000)  { i = 2; L = 40000;  KW = 64;  nch = 1250; pp = p2; W = w2; Bb = b2; H = h2 + (size_t)row * 64; }
    else                  { i = 3; L = 200000; KW = 16;  nch = 530;  pp = p3; W = w3; Bb = b3; H = h3 + (size_t)row * 32; }
    float lseT = lse_chunks(pp + (size_t)row * nch, nch);
    int ti = t - L;
    float tsel = dot_bw(H, W + (size_t)ti * KW, KW) + Bb[ti];
    int j = 3 - i;  // head_lp[:, -i] == cluster row (3-i)
    float csel = dot_bw(h0 + (size_t)row * 1024, cluster_w + (size_t)j * 1024, 1024) + cluster_b[j];
    lp = (csel - lseH) + (tsel - lseT);
  }
  if (lane == 0) out[row] = -lp;
}

extern "C" void kernel_launch(void* const* d_in, const int* in_sizes, int n_in,
                              void* d_out, int out_size, void* d_ws, size_t ws_size,
                              hipStream_t stream) {
  (void)in_sizes; (void)n_in; (void)out_size; (void)ws_size;
  const float* hidden    = (const float*)d_in[0];
  const int*   target    = (const int*)d_in[1];
  const float* head_w    = (const float*)d_in[2];
  const float* head_b    = (const float*)d_in[3];
  const float* cluster_w = (const float*)d_in[4];
  const float* cluster_b = (const float*)d_in[5];
  const float* proj0     = (const float*)d_in[6];
  const float* proj1     = (const float*)d_in[7];
  const float* proj2     = (const float*)d_in[8];
  const float* proj3     = (const float*)d_in[9];
  const float* w1 = (const float*)d_in[10];
  const float* b1 = (const float*)d_in[11];
  const float* w2 = (const float*)d_in[12];
  const float* b2 = (const float*)d_in[13];
  const float* w3 = (const float*)d_in[14];
  const float* b3 = (const float*)d_in[15];
  float* out = (float*)d_out;

  char* p = (char*)d_ws;
  bf16* hid_b = (bf16*)p; p += (size_t)1024 * 1024 * 2;
  bf16* h0    = (bf16*)p; p += (size_t)1024 * 1024 * 2;
  bf16* h1    = (bf16*)p; p += (size_t)1024 * 256 * 2;
  bf16* h2    = (bf16*)p; p += (size_t)1024 * 64 * 2;
  bf16* h3    = (bf16*)p; p += (size_t)1024 * 32 * 2;   // K padded 16->32 (zeros)
  bf16* Wh    = (bf16*)p; p += (size_t)20096 * 1024 * 2; // head_w ++ cluster_w, row-pad
  bf16* W1b   = (bf16*)p; p += (size_t)20096 * 256 * 2;
  bf16* W2b   = (bf16*)p; p += (size_t)160000 * 64 * 2;
  bf16* W3b   = (bf16*)p; p += (size_t)67840 * 32 * 2;
  bf16* P0t   = (bf16*)p; p += (size_t)1024 * 1024 * 2;
  bf16* P1t   = (bf16*)p; p += (size_t)256 * 1024 * 2;
  bf16* P2t   = (bf16*)p; p += (size_t)128 * 1024 * 2;
  bf16* P3t   = (bf16*)p; p += (size_t)128 * 1024 * 2;
  float* pH   = (float*)p; p += (size_t)1024 * 157 * 4;
  float* p1   = (float*)p; p += (size_t)1024 * 157 * 4;
  float* p2   = (float*)p; p += (size_t)1024 * 1250 * 4;
  float* p3   = (float*)p; p += (size_t)1024 * 530 * 4;

  hipMemsetAsync(h3, 0, (size_t)1024 * 32 * 2, stream);

  // ---- weight/input conversion passes ----
  convert_bf16_kernel<<<1024, 256, 0, stream>>>(hidden, hid_b, 262144);
  convert_bf16_kernel<<<20000, 256, 0, stream>>>(head_w, Wh, 5120000);
  convert_bf16_kernel<<<3, 256, 0, stream>>>(cluster_w, Wh + (size_t)20000 * 1024, 768);
  convert_bf16_kernel<<<5000, 256, 0, stream>>>(w1, W1b, 1280000);
  convert_bf16_kernel<<<10000, 256, 0, stream>>>(w2, W2b, 2560000);
  convert_w3_kernel<<<1059, 256, 0, stream>>>(w3, W3b, 270940);
  transpose_convert_kernel<<<dim3(32, 32), 256, 0, stream>>>(proj0, P0t, 1024);
  transpose_convert_kernel<<<dim3(32, 8), 256, 0, stream>>>(proj1, P1t, 256);
  transpose_convert_kernel<<<dim3(32, 2), 256, 0, stream>>>(proj2, P2t, 64);
  transpose_convert_kernel<<<dim3(32, 1), 256, 0, stream>>>(proj3, P3t, 16);

  // ---- projection GEMMs: hX = hid_b @ PXt^T ----
  gemm_kernel<1024, false><<<64, 256, 0, stream>>>(hid_b, P0t, nullptr, nullptr, 0, 0,
                                                   nullptr, 8, h0, 1024, 1024);
  gemm_kernel<1024, false><<<64, 256, 0, stream>>>(hid_b, P1t, nullptr, nullptr, 0, 0,
                                                   nullptr, 2, h1, 256, 256);
  gemm_kernel<1024, false><<<64, 256, 0, stream>>>(hid_b, P2t, nullptr, nullptr, 0, 0,
                                                   nullptr, 1, h2, 64, 64);
  gemm_kernel<1024, false><<<64, 256, 0, stream>>>(hid_b, P3t, nullptr, nullptr, 0, 0,
                                                   nullptr, 1, h3, 32, 16);

  // ---- fused GEMM + chunk logsumexp ----
  const int BIG = 0x40000000;
  gemm_kernel<1024, true><<<64 * 20, 256, 0, stream>>>(h0, Wh, head_b, cluster_b, 20000, 20003,
                                                       pH, 157, nullptr, 0, 0);
  gemm_kernel<256, true><<<64 * 20, 256, 0, stream>>>(h1, W1b, b1, b1, BIG, 20000,
                                                      p1, 157, nullptr, 0, 0);
  gemm_kernel<64, true><<<64 * 157, 256, 0, stream>>>(h2, W2b, b2, b2, BIG, 160000,
                                                      p2, 1250, nullptr, 0, 0);
  gemm_kernel<32, true><<<64 * 67, 256, 0, stream>>>(h3, W3b, b3, b3, BIG, 67735,
                                                     p3, 530, nullptr, 0, 0);

  final_kernel<<<256, 256, 0, stream>>>(target, pH, p1, p2, p3, h0, h1, h2, h3,
                                        head_w, head_b, cluster_w, cluster_b,
                                        w1, b1, w2, b2, w3, b3, out);
}

// Round 4
// 454.242 us; speedup vs baseline: 3.2409x; 1.4394x over previous
//
#include <hip/hip_runtime.h>
#include <math.h>

typedef __bf16 bf16;
typedef __bf16 bf16x4 __attribute__((ext_vector_type(4)));
typedef __bf16 bf16x8 __attribute__((ext_vector_type(8)));
typedef float  f32x4  __attribute__((ext_vector_type(4)));

__device__ __forceinline__ f32x4 mfma16x16x32(bf16x8 a, bf16x8 b, f32x4 c) {
  return __builtin_amdgcn_mfma_f32_16x16x32_bf16(a, b, c, 0, 0, 0);
}

// async 16B global -> LDS (lane data lands at ldsbase + lane*16)
__device__ __forceinline__ void async16(const bf16* gp, bf16* lp) {
  __builtin_amdgcn_global_load_lds(
      (const __attribute__((address_space(1))) void*)gp,
      (__attribute__((address_space(3))) void*)lp, 16, 0, 0);
}

// ---------------- fp32 -> bf16 convert ----------------
__global__ void __launch_bounds__(256) convert_bf16_kernel(const float* __restrict__ in,
                                                           bf16* __restrict__ out, int n4) {
  int i = blockIdx.x * 256 + threadIdx.x;
  if (i < n4) {
    float4 f = ((const float4*)in)[i];
    bf16x4 b = {(bf16)f.x, (bf16)f.y, (bf16)f.z, (bf16)f.w};
    ((bf16x4*)out)[i] = b;
  }
}

// w3 [67735][16] fp32 -> W3b [67840][32] bf16, k 16..31 zeroed
__global__ void __launch_bounds__(256) convert_w3_kernel(const float* __restrict__ w3,
                                                         bf16* __restrict__ W3b, int n4) {
  int i = blockIdx.x * 256 + threadIdx.x;
  if (i >= n4) return;
  int row = i >> 2, kq = i & 3;
  float4 f = *(const float4*)&w3[(size_t)i * 4];
  bf16x4 b = {(bf16)f.x, (bf16)f.y, (bf16)f.z, (bf16)f.w};
  *(bf16x4*)&W3b[(size_t)row * 32 + kq * 4] = b;
  bf16x4 z = {(bf16)0.f, (bf16)0.f, (bf16)0.f, (bf16)0.f};
  *(bf16x4*)&W3b[(size_t)row * 32 + 16 + kq * 4] = z;
}

// P [1024][dX] fp32 -> Pt [*][1024] bf16 (transpose+convert, zero-pad cols>=dX)
__global__ void __launch_bounds__(256) transpose_convert_kernel(const float* __restrict__ P,
                                                                bf16* __restrict__ Pt, int dX) {
  __shared__ float t[32][33];
  int tx = threadIdx.x & 31, ty = threadIdx.x >> 5;
  int k0 = blockIdx.x * 32, c0 = blockIdx.y * 32;
#pragma unroll
  for (int s = 0; s < 4; ++s) {
    int k = k0 + ty + s * 8, col = c0 + tx;
    t[ty + s * 8][tx] = (col < dX) ? P[(size_t)k * dX + col] : 0.f;
  }
  __syncthreads();
#pragma unroll
  for (int s = 0; s < 4; ++s) {
    int colo = c0 + ty + s * 8;
    Pt[(size_t)colo * 1024 + k0 + tx] = (bf16)t[tx][ty + s * 8];
  }
}

// ---------------- row compaction by target cluster ----------------
// rowmap[c*1152 + slot] = row ; slotmap[row] = slot ; counts[c]
__global__ void __launch_bounds__(1024) compact_kernel(const int* __restrict__ target,
                                                       int* __restrict__ rowmap,
                                                       int* __restrict__ slotmap,
                                                       int* __restrict__ counts) {
  __shared__ int cnt[3];
  int tid = threadIdx.x;
  if (tid < 3) cnt[tid] = 0;
  for (int i = tid; i < 3 * 1152; i += 1024) rowmap[i] = 0;
  __syncthreads();
  int t = target[tid];
  int c = (t >= 200000) ? 2 : (t >= 40000) ? 1 : (t >= 20000) ? 0 : -1;
  int slot = -1;
  if (c >= 0) {
    slot = atomicAdd(&cnt[c], 1);
    rowmap[c * 1152 + slot] = tid;
  }
  slotmap[tid] = slot;
  __syncthreads();
  if (tid < 3) counts[tid] = cnt[tid];
}

// ---------------- unified MFMA GEMM (128x128 tile, async staging) ----------------
// A rows indirected via rmap (nullptr = identity); cntp: early-exit row-block bound.
// LSE=true: per-wave-max logsumexp partial, chunk-major part[chunk*1024+slot].
template <int KDIM, bool LSE>
__global__ void __launch_bounds__(256) gemm_kernel(
    const bf16* __restrict__ A, int strideA,
    const int* __restrict__ rmap, const int* __restrict__ cntp,
    const bf16* __restrict__ B,
    const float* __restrict__ bias, const float* __restrict__ bias2,
    int splice, int V, float* __restrict__ part, int nchunk,
    bf16* __restrict__ Out, int strideOut, int dX) {
  constexpr int BK = (KDIM < 64) ? KDIM : 64;   // 32 or 64
  constexpr int KG = BK / 8;                    // 4 or 8 granules
  constexpr int NIT = KDIM / BK;
  __shared__ bf16 Alds[128 * BK];
  __shared__ bf16 Blds[128 * BK];
  __shared__ float2 wpart[2][128];

  const int tid = threadIdx.x;
  const int w = tid >> 6, lane = tid & 63;
  const int q = lane >> 4, c = lane & 15;
  const int wr = w >> 1, wc = w & 1;

  int f = blockIdx.x;
  int xr = f & 7, rb = (f >> 3) & 7, cq = f >> 6;
  int chunk = cq * 8 + xr;
  if (chunk >= nchunk) return;
  const int row0 = rb * 128, col0 = chunk * 128;
  if (cntp && row0 >= *cntp) return;

  // per-thread A-row assignment is fixed across k-tiles; resolve indirection once
  int arow[KG / 2];
#pragma unroll
  for (int i = 0; i < KG / 2; ++i) {
    int g = i * 256 + tid;
    int r = row0 + g / KG;
    arow[i] = rmap ? rmap[r] : r;
  }

  f32x4 acc[4][4] = {};

  for (int kt = 0; kt < NIT; ++kt) {
    const int k0 = kt * BK;
#pragma unroll
    for (int i = 0; i < KG / 2; ++i) {
      int g = i * 256 + tid;
      int col = g / KG, j = g % KG;
      int kg = (KG == 8) ? (j ^ (col & 7)) : (j ^ ((col >> 1) & 3));
      bf16* abase = &Alds[(size_t)(g & ~63) * 8];
      bf16* bbase = &Blds[(size_t)(g & ~63) * 8];
      async16(A + (size_t)arow[i] * strideA + k0 + kg * 8, abase);
      async16(B + (size_t)(col0 + col) * KDIM + k0 + kg * 8, bbase);
    }
    __syncthreads();
#pragma unroll
    for (int ks = 0; ks < BK / 32; ++ks) {
      bf16x8 af[4], bfr[4];
#pragma unroll
      for (int rt = 0; rt < 4; ++rt) {
        int rl = wr * 64 + rt * 16 + c;
        int kq = ks * 4 + q;
        int kg = (KG == 8) ? (kq ^ (rl & 7)) : (kq ^ ((rl >> 1) & 3));
        af[rt] = *(const bf16x8*)&Alds[((size_t)rl * KG + kg) * 8];
      }
#pragma unroll
      for (int ct = 0; ct < 4; ++ct) {
        int cl = wc * 64 + ct * 16 + c;
        int kq = ks * 4 + q;
        int kg = (KG == 8) ? (kq ^ (cl & 7)) : (kq ^ ((cl >> 1) & 3));
        bfr[ct] = *(const bf16x8*)&Blds[((size_t)cl * KG + kg) * 8];
      }
#pragma unroll
      for (int rt = 0; rt < 4; ++rt)
#pragma unroll
        for (int ct = 0; ct < 4; ++ct)
          acc[rt][ct] = mfma16x16x32(af[rt], bfr[ct], acc[rt][ct]);
    }
    __syncthreads();
  }

  if (!LSE) {
#pragma unroll
    for (int rt = 0; rt < 4; ++rt)
#pragma unroll
      for (int ct = 0; ct < 4; ++ct)
#pragma unroll
        for (int r = 0; r < 4; ++r) {
          int col = col0 + wc * 64 + ct * 16 + c;
          if (col < dX) {
            int row = row0 + wr * 64 + rt * 16 + q * 4 + r;
            Out[(size_t)row * strideOut + col] = (bf16)acc[rt][ct][r];
          }
        }
    return;
  }

  // ---- LSE epilogue: wave-wide max (safe: logit spread << 87), native exp ----
  float bv[4];
#pragma unroll
  for (int ct = 0; ct < 4; ++ct) {
    int colg = col0 + wc * 64 + ct * 16 + c;
    bv[ct] = (colg < V) ? ((colg < splice) ? bias[colg] : bias2[colg - splice]) : -INFINITY;
  }
  float M = -INFINITY;
#pragma unroll
  for (int rt = 0; rt < 4; ++rt)
#pragma unroll
    for (int ct = 0; ct < 4; ++ct)
#pragma unroll
      for (int r = 0; r < 4; ++r) {
        acc[rt][ct][r] += bv[ct];
        M = fmaxf(M, acc[rt][ct][r]);
      }
#pragma unroll
  for (int off = 1; off < 64; off <<= 1) M = fmaxf(M, __shfl_xor(M, off));
  if (M == -INFINITY) M = 0.f;   // all-cols-invalid wave

#pragma unroll
  for (int rt = 0; rt < 4; ++rt) {
#pragma unroll
    for (int r = 0; r < 4; ++r) {
      float s = 0.f;
#pragma unroll
      for (int ct = 0; ct < 4; ++ct) s += __expf(acc[rt][ct][r] - M);
#pragma unroll
      for (int off = 1; off <= 8; off <<= 1) s += __shfl_xor(s, off);
      if (c == 0) wpart[wc][wr * 64 + rt * 16 + q * 4 + r] = make_float2(M, s);
    }
  }
  __syncthreads();
  if (tid < 128) {
    float2 a = wpart[0][tid], b = wpart[1][tid];
    float m = fmaxf(a.x, b.x);
    float s = a.y * __expf(a.x - m) + b.y * __expf(b.x - m);
    part[(size_t)chunk * 1024 + row0 + tid] = m + __logf(s);
  }
}

// ---------------- final combine ----------------
__device__ __forceinline__ float wave_max64(float v) {
#pragma unroll
  for (int off = 1; off < 64; off <<= 1) v = fmaxf(v, __shfl_xor(v, off));
  return v;
}
__device__ __forceinline__ float wave_sum64(float v) {
#pragma unroll
  for (int off = 1; off < 64; off <<= 1) v += __shfl_xor(v, off);
  return v;
}
// chunk-major partials: p[i*1024 + idx]
__device__ float lse_cm(const float* __restrict__ p, int n, int idx) {
  int lane = threadIdx.x & 63;
  float m = -INFINITY;
  for (int i = lane; i < n; i += 64) m = fmaxf(m, p[(size_t)i * 1024 + idx]);
  m = wave_max64(m);
  float s = 0.f;
  for (int i = lane; i < n; i += 64) s += __expf(p[(size_t)i * 1024 + idx] - m);
  s = wave_sum64(s);
  return m + __logf(s);
}
__device__ float dot_bw(const bf16* __restrict__ h, const float* __restrict__ wv, int K) {
  int lane = threadIdx.x & 63;
  float s = 0.f;
  for (int i = lane; i < K; i += 64) s += (float)h[i] * wv[i];
  return wave_sum64(s);
}

__global__ void __launch_bounds__(256) final_kernel(
    const int* __restrict__ target, const int* __restrict__ slotmap,
    const float* __restrict__ pH, const float* __restrict__ p1,
    const float* __restrict__ p2, const float* __restrict__ p3,
    const bf16* __restrict__ Hcat,
    const float* __restrict__ head_w, const float* __restrict__ head_b,
    const float* __restrict__ cluster_w, const float* __restrict__ cluster_b,
    const float* __restrict__ w1, const float* __restrict__ b1,
    const float* __restrict__ w2, const float* __restrict__ b2,
    const float* __restrict__ w3, const float* __restrict__ b3,
    float* __restrict__ out) {
  int wv = threadIdx.x >> 6, lane = threadIdx.x & 63;
  int row = blockIdx.x * 4 + wv;
  int t = target[row];
  const bf16* h0 = Hcat + (size_t)row * 1408;

  float lseH = lse_cm(pH, 157, row);
  float lp;
  if (t < 20000) {
    float sel = dot_bw(h0, head_w + (size_t)t * 1024, 1024) + head_b[t];
    lp = sel - lseH;
  } else {
    int i, L, KW, nch, hoff;
    const float* pp; const float* W; const float* Bb;
    if (t < 40000)        { i = 1; L = 20000;  KW = 256; nch = 157;  hoff = 1024; pp = p1; W = w1; Bb = b1; }
    else if (t < 200000)  { i = 2; L = 40000;  KW = 64;  nch = 1250; hoff = 1280; pp = p2; W = w2; Bb = b2; }
    else                  { i = 3; L = 200000; KW = 16;  nch = 530;  hoff = 1344; pp = p3; W = w3; Bb = b3; }
    int slot = slotmap[row];
    float lseT = lse_cm(pp, nch, slot);
    int ti = t - L;
    float tsel = dot_bw(h0 + hoff, W + (size_t)ti * KW, KW) + Bb[ti];
    int j = 3 - i;  // head_lp[:, -i] == cluster row (3-i)
    float csel = dot_bw(h0, cluster_w + (size_t)j * 1024, 1024) + cluster_b[j];
    lp = (csel - lseH) + (tsel - lseT);
  }
  if (lane == 0) out[row] = -lp;
}

extern "C" void kernel_launch(void* const* d_in, const int* in_sizes, int n_in,
                              void* d_out, int out_size, void* d_ws, size_t ws_size,
                              hipStream_t stream) {
  (void)in_sizes; (void)n_in; (void)out_size; (void)ws_size;
  const float* hidden    = (const float*)d_in[0];
  const int*   target    = (const int*)d_in[1];
  const float* head_w    = (const float*)d_in[2];
  const float* head_b    = (const float*)d_in[3];
  const float* cluster_w = (const float*)d_in[4];
  const float* cluster_b = (const float*)d_in[5];
  const float* proj0     = (const float*)d_in[6];
  const float* proj1     = (const float*)d_in[7];
  const float* proj2     = (const float*)d_in[8];
  const float* proj3     = (const float*)d_in[9];
  const float* w1 = (const float*)d_in[10];
  const float* b1 = (const float*)d_in[11];
  const float* w2 = (const float*)d_in[12];
  const float* b2 = (const float*)d_in[13];
  const float* w3 = (const float*)d_in[14];
  const float* b3 = (const float*)d_in[15];
  float* out = (float*)d_out;

  char* p = (char*)d_ws;
  bf16* hid_b = (bf16*)p; p += (size_t)1024 * 1024 * 2;
  bf16* Hcat  = (bf16*)p; p += (size_t)1024 * 1408 * 2;  // h0|h1|h2|h3 stride 1408
  bf16* Pcat  = (bf16*)p; p += (size_t)1408 * 1024 * 2;  // P0t|P1t|P2t|P3t stacked
  bf16* Wh    = (bf16*)p; p += (size_t)20096 * 1024 * 2; // head_w ++ cluster_w
  bf16* W1b   = (bf16*)p; p += (size_t)20096 * 256 * 2;
  bf16* W2b   = (bf16*)p; p += (size_t)160000 * 64 * 2;
  bf16* W3b   = (bf16*)p; p += (size_t)67840 * 32 * 2;
  float* pH   = (float*)p; p += (size_t)157 * 1024 * 4;
  float* p1   = (float*)p; p += (size_t)157 * 1024 * 4;
  float* p2   = (float*)p; p += (size_t)1250 * 1024 * 4;
  float* p3   = (float*)p; p += (size_t)530 * 1024 * 4;
  int* rowmap = (int*)p;  p += 3 * 1152 * 4;
  int* slotmap= (int*)p;  p += 1024 * 4;
  int* counts = (int*)p;  p += 3 * 4;

  compact_kernel<<<1, 1024, 0, stream>>>(target, rowmap, slotmap, counts);

  // ---- weight/input conversion ----
  convert_bf16_kernel<<<1024, 256, 0, stream>>>(hidden, hid_b, 262144);
  convert_bf16_kernel<<<20000, 256, 0, stream>>>(head_w, Wh, 5120000);
  convert_bf16_kernel<<<3, 256, 0, stream>>>(cluster_w, Wh + (size_t)20000 * 1024, 768);
  convert_bf16_kernel<<<5000, 256, 0, stream>>>(w1, W1b, 1280000);
  convert_bf16_kernel<<<10000, 256, 0, stream>>>(w2, W2b, 2560000);
  convert_w3_kernel<<<1059, 256, 0, stream>>>(w3, W3b, 270940);
  transpose_convert_kernel<<<dim3(32, 32), 256, 0, stream>>>(proj0, Pcat, 1024);
  transpose_convert_kernel<<<dim3(32, 8), 256, 0, stream>>>(proj1, Pcat + (size_t)1024 * 1024, 256);
  transpose_convert_kernel<<<dim3(32, 2), 256, 0, stream>>>(proj2, Pcat + (size_t)1280 * 1024, 64);
  transpose_convert_kernel<<<dim3(32, 1), 256, 0, stream>>>(proj3, Pcat + (size_t)1344 * 1024, 16);

  // ---- all projections in one GEMM: Hcat[1024][1376] = hid_b @ Pcat^T ----
  gemm_kernel<1024, false><<<128, 256, 0, stream>>>(hid_b, 1024, nullptr, nullptr, Pcat,
                                                    nullptr, nullptr, 0, 0, nullptr, 11,
                                                    Hcat, 1408, 1376);

  // ---- fused GEMM + chunk logsumexp ----
  gemm_kernel<1024, true><<<64 * 20, 256, 0, stream>>>(Hcat, 1408, nullptr, nullptr, Wh,
                                                       head_b, cluster_b, 20000, 20003,
                                                       pH, 157, nullptr, 0, 0);
  gemm_kernel<256, true><<<64 * 20, 256, 0, stream>>>(Hcat + 1024, 1408, rowmap, counts, W1b,
                                                      b1, b1, 0x40000000, 20000,
                                                      p1, 157, nullptr, 0, 0);
  gemm_kernel<64, true><<<64 * 157, 256, 0, stream>>>(Hcat + 1280, 1408, rowmap + 1152, counts + 1, W2b,
                                                      b2, b2, 0x40000000, 160000,
                                                      p2, 1250, nullptr, 0, 0);
  gemm_kernel<32, true><<<64 * 67, 256, 0, stream>>>(Hcat + 1344, 1408, rowmap + 2304, counts + 2, W3b,
                                                     b3, b3, 0x40000000, 67735,
                                                     p3, 530, nullptr, 0, 0);

  final_kernel<<<256, 256, 0, stream>>>(target, slotmap, pH, p1, p2, p3, Hcat,
                                        head_w, head_b, cluster_w, cluster_b,
                                        w1, b1, w2, b2, w3, b3, out);
}